// Round 9
// baseline (77364.966 us; speedup 1.0000x reference)
//
#include <hip/hip_runtime.h>
#include <hip/hip_bf16.h>

typedef __attribute__((ext_vector_type(8))) _Float16 half8_t;
typedef __attribute__((ext_vector_type(4))) float f32x4_t;
typedef unsigned long long u64;

#define S0W 1544                    // LDS row stride (elems): 1536 + 8 pad
#define LDS_BYTES (16 * S0W * 2)    // 49408 B (W0 plane-1, 16-col slice)

__device__ __forceinline__ float sigm(float z) { return 1.0f / (1.0f + __expf(-z)); }
__device__ __forceinline__ float tanh_fast(float z) {
  float e = __expf(2.0f * z);
  return 1.0f - 2.0f / (e + 1.0f);
}

// ---- coherent (cross-XCD) access helpers
__device__ __forceinline__ half8_t ld_h8_coh(const _Float16* p) {
  union { half8_t h; u64 q[2]; } r;
  u64* q = (u64*)p;
  r.q[0] = __hip_atomic_load(q,     __ATOMIC_RELAXED, __HIP_MEMORY_SCOPE_SYSTEM);
  r.q[1] = __hip_atomic_load(q + 1, __ATOMIC_RELAXED, __HIP_MEMORY_SCOPE_SYSTEM);
  return r.h;
}
__device__ __forceinline__ void st_h_coh(_Float16* p, _Float16 v) {
  unsigned short b = __builtin_bit_cast(unsigned short, v);
  __hip_atomic_store((unsigned short*)p, b, __ATOMIC_RELAXED, __HIP_MEMORY_SCOPE_SYSTEM);
}
__device__ __forceinline__ float ld_f_coh(const float* p) {
  return __hip_atomic_load((float*)p, __ATOMIC_RELAXED, __HIP_MEMORY_SCOPE_SYSTEM);
}
__device__ __forceinline__ void st_f_coh(float* p, float v) {
  __hip_atomic_store(p, v, __ATOMIC_RELAXED, __HIP_MEMORY_SCOPE_SYSTEM);
}

// ws layout (bytes) — total 59,940,864 < known-good 60,395,520:
//   W0a  @ 0         : 12582912   (fp16 plane1 = fp16(32*w), [gp][k])
//   W0b  @ 12582912  : 12582912
//   W1a  @ 25165824  : 16777216
//   W1b  @ 41943040  : 16777216
//   vecs @ 58720256  : 98304
//   hch  @ 58818560  : 524288     (h plane1 fp16, [row][h0|h1])
//   hcm  @ 59342848  : 524288     (h plane2 fp16, residual*2048)
//   stats@ 59867136  : 65536      (16 reps x 4 bufs x 256 f32)
//   bars @ 59932672  : 8192

// permutation (16-col groups): gp = colgrp*16 + c ; gate=c>>2, uo=c&3
//   gcol = gate*1024 + colgrp*4 + uo      (colgrp 0..255)
__global__ void lstm_prep(const float* __restrict__ W0, const float* __restrict__ W1,
                          const float* __restrict__ b0, const float* __restrict__ g0,
                          const float* __restrict__ be0, const float* __restrict__ b1,
                          const float* __restrict__ g1, const float* __restrict__ be1,
                          _Float16* __restrict__ W0a, _Float16* __restrict__ W0b,
                          _Float16* __restrict__ W1a, _Float16* __restrict__ W1b,
                          float* __restrict__ vecs)
{
  int gid = blockIdx.x * 256 + threadIdx.x;
  const int W0N = 192 * 4096;
  const int W1N = 256 * 4096;
  if (gid < W0N) {
    int k8 = gid >> 12, gp = gid & 4095;
    int colgrp = gp >> 4, c = gp & 15;
    int gcol = ((c >> 2) << 10) + (colgrp << 2) + (c & 3);
    half8_t va, vb;
    #pragma unroll
    for (int j = 0; j < 8; ++j) {
      float w32 = W0[(size_t)(k8 * 8 + j) * 4096 + gcol] * 32.0f;
      _Float16 p1 = (_Float16)w32;
      float r = w32 - (float)p1;
      va[j] = p1; vb[j] = (_Float16)(r * 2048.0f);
    }
    *(half8_t*)&W0a[(size_t)gp * 1536 + k8 * 8] = va;
    *(half8_t*)&W0b[(size_t)gp * 1536 + k8 * 8] = vb;
  } else if (gid < W0N + W1N) {
    int g2 = gid - W0N;
    int k8 = g2 >> 12, gp = g2 & 4095;
    int colgrp = gp >> 4, c = gp & 15;
    int gcol = ((c >> 2) << 10) + (colgrp << 2) + (c & 3);
    half8_t va, vb;
    #pragma unroll
    for (int j = 0; j < 8; ++j) {
      float w32 = W1[(size_t)(k8 * 8 + j) * 4096 + gcol] * 32.0f;
      _Float16 p1 = (_Float16)w32;
      float r = w32 - (float)p1;
      va[j] = p1; vb[j] = (_Float16)(r * 2048.0f);
    }
    *(half8_t*)&W1a[(size_t)gp * 2048 + k8 * 8] = va;
    *(half8_t*)&W1b[(size_t)gp * 2048 + k8 * 8] = vb;
  } else if (gid < W0N + W1N + 6 * 4096) {
    int g2 = gid - W0N - W1N;
    int j = g2 >> 12, gp = g2 & 4095;
    int colgrp = gp >> 4, c = gp & 15;
    int gcol = ((c >> 2) << 10) + (colgrp << 2) + (c & 3);
    const float* src = (j == 0) ? b0 : (j == 1) ? g0 : (j == 2) ? be0
                     : (j == 3) ? b1 : (j == 4) ? g1 : be1;
    vecs[j * 4096 + gp] = src[gcol];
  }
}

#define MFMA16(A, B, C) __builtin_amdgcn_mfma_f32_16x16x32_f16(A, B, C, 0, 0, 0)

// ---- fence-free grid barrier, 256 arrivals (r7-proven 8x32 structure)
__device__ __forceinline__ void gridbar(unsigned* bars, int wgid, int tid, unsigned ep) {
  __syncthreads();
  if (tid == 0) {
    const int q = ep & 1;
    unsigned old = __hip_atomic_fetch_add(&bars[(q * 8 + (wgid & 7)) * 32], 1u,
                                          __ATOMIC_RELAXED, __HIP_MEMORY_SCOPE_AGENT);
    if (old == 31u) {
      unsigned mo = __hip_atomic_fetch_add(&bars[512 + q * 32], 1u,
                                           __ATOMIC_RELAXED, __HIP_MEMORY_SCOPE_AGENT);
      if (mo == 7u) {
        #pragma unroll
        for (int g = 0; g < 8; ++g)
          __hip_atomic_store(&bars[(q * 8 + g) * 32], 0u, __ATOMIC_RELAXED, __HIP_MEMORY_SCOPE_SYSTEM);
        __hip_atomic_store(&bars[512 + q * 32], 0u, __ATOMIC_RELAXED, __HIP_MEMORY_SCOPE_SYSTEM);
        __hip_atomic_store(&bars[576], ep, __ATOMIC_RELEASE, __HIP_MEMORY_SCOPE_SYSTEM);
      }
    }
    while (__hip_atomic_load(&bars[576], __ATOMIC_RELAXED, __HIP_MEMORY_SCOPE_SYSTEM) < ep) {}
  }
  __syncthreads();
}

// 256 WGs x 512 thr (8 waves = 2 waves/SIMD). WG = colgrp (16 cols) x all 128 rows;
// wave wid = mtile 0..7, one col-tile per wave.
__global__ void __launch_bounds__(512, 2) lstm_seq(
    const float* __restrict__ x,
    const _Float16* __restrict__ W0ap,
    const _Float16* __restrict__ W0bp,
    const _Float16* __restrict__ W1ap,
    const _Float16* __restrict__ W1bp,
    const float* __restrict__ vecs,
    _Float16* __restrict__ hch,
    _Float16* __restrict__ hcm,
    float* __restrict__ stats,
    unsigned* __restrict__ bars,
    const float* __restrict__ fcW,
    const float* __restrict__ fcb,
    float* __restrict__ out)
{
  extern __shared__ _Float16 W0s[];   // [16][S0W] plane-1 (scaled x32)
  const int tid = threadIdx.x;
  const int wgid = blockIdx.x;
  const int colgrp = wgid;             // 0..255, 16-col group
  const int wid = tid >> 6;            // 0..7 = mtile
  const int lane = tid & 63;
  const int c16 = lane & 15;
  const int klo = lane >> 4;

  for (int i = tid; i < 16 * 192; i += 512) {
    int r = i / 192, ch = i - r * 192;
    *(half8_t*)&W0s[r * S0W + ch * 8] =
        *(const half8_t*)&W0ap[((size_t)colgrp * 16 + r) * 1536 + ch * 8];
  }
  __syncthreads();

  const int gp = colgrp * 16 + c16;
  const float b0v  = vecs[gp];
  const float g0v  = vecs[4096 + gp];
  const float be0v = vecs[8192 + gp];
  const float b1v  = vecs[12288 + gp];
  const float g1v  = vecs[16384 + gp];
  const float be1v = vecs[20480 + gp];

  const int mtile = wid;                             // 0..7
  const int arow = mtile * 16 + c16;
  const float* xbase = x + (size_t)arow * 512 * 512; // x[row][t][d]
  const _Float16* hrh = hch + arow * 2048;
  const _Float16* hrm = hcm + arow * 2048;
  const _Float16* w0m = W0bp + (size_t)gp * 1536;
  const _Float16* w1a = W1ap + (size_t)gp * 2048;
  const _Float16* w1b = W1bp + (size_t)gp * 2048;
  const int repbase = (wgid & 15) << 2;              // rep*4 for stats writes

  float c0s[4] = {0,0,0,0};
  float c1s[4] = {0,0,0,0};
  unsigned ep = 0;

#define SPLIT2(E, J) { float e_ = (E); _Float16 h1_ = (_Float16)e_;           \
  float r_ = e_ - (float)h1_; ah[J] = h1_; am[J] = (_Float16)(r_ * 2048.0f); }

#define PROD3(HA, MA) \
  HA = MFMA16(ah, bh0, HA);                                                   \
  MA = MFMA16(ah, bm0, MA);                                                   \
  MA = MFMA16(am, bh0, MA);

#define X_BODY(KB, HA, MA) {                                                  \
      float4 xu = *(const float4*)(xp + (KB) * 32);                           \
      float4 xw = *(const float4*)(xp + (KB) * 32 + 4);                       \
      half8_t ah, am;                                                         \
      SPLIT2(xu.x, 0) SPLIT2(xu.y, 1) SPLIT2(xu.z, 2) SPLIT2(xu.w, 3)         \
      SPLIT2(xw.x, 4) SPLIT2(xw.y, 5) SPLIT2(xw.z, 6) SPLIT2(xw.w, 7)         \
      half8_t bh0 = *(const half8_t*)&W0s[c16 * S0W + (KB) * 32 + klo * 8];   \
      half8_t bm0 = *(const half8_t*)&w0m[(KB) * 32 + klo * 8];               \
      PROD3(HA, MA) }

#define H0_BODY(KB, HA, MA) {                                                 \
      half8_t ah = ld_h8_coh(&hrh[(KB) * 32 + klo * 8]);                      \
      half8_t am = ld_h8_coh(&hrm[(KB) * 32 + klo * 8]);                      \
      half8_t bh0 = *(const half8_t*)&W0s[c16 * S0W + 512 + (KB) * 32 + klo * 8]; \
      half8_t bm0 = *(const half8_t*)&w0m[512 + (KB) * 32 + klo * 8];         \
      PROD3(HA, MA) }

#define H1_BODY(KB, HA, MA) {                                                 \
      half8_t ah = ld_h8_coh(&hrh[(KB) * 32 + klo * 8]);                      \
      half8_t am = ld_h8_coh(&hrm[(KB) * 32 + klo * 8]);                      \
      half8_t bh0 = *(const half8_t*)&w1a[(KB) * 32 + klo * 8];               \
      half8_t bm0 = *(const half8_t*)&w1b[(KB) * 32 + klo * 8];               \
      PROD3(HA, MA) }

#define STAT_ADD(V, BUF) {                                                    \
    _Pragma("unroll")                                                         \
    for (int r = 0; r < 4; ++r) {                                             \
      float s = V[r];                                                         \
      float q = V[r]*V[r];                                                    \
      _Pragma("unroll")                                                       \
      for (int m = 1; m <= 8; m <<= 1) { s += __shfl_xor(s, m); q += __shfl_xor(q, m); } \
      if (c16 == 0) {                                                         \
        int row = mtile * 16 + klo * 4 + r;                                   \
        atomicAdd(&stats[(repbase + (BUF)) * 256 + row * 2 + 0], s);          \
        atomicAdd(&stats[(repbase + (BUF)) * 256 + row * 2 + 1], q);          \
      }                                                                       \
    } }

// LN + LSTM cell. Stats read: lane c16 loads replica c16, shuffle-sum (16 reps).
#define CELL(V, BUF, CS, GC, BEC, HB) {                                       \
    _Pragma("unroll")                                                         \
    for (int r = 0; r < 4; ++r) {                                             \
      int row = mtile * 16 + klo * 4 + r;                                     \
      const float* sp = stats + ((c16 << 2) + (BUF)) * 256 + row * 2;         \
      float s_ = ld_f_coh(sp), q_ = ld_f_coh(sp + 1);                         \
      _Pragma("unroll")                                                       \
      for (int m = 1; m <= 8; m <<= 1) { s_ += __shfl_xor(s_, m); q_ += __shfl_xor(q_, m); } \
      float mean = s_ * (1.0f / 4096.0f);                                     \
      float msq  = q_ * (1.0f / 4096.0f);                                     \
      float rstd = rsqrtf(msq - mean * mean + 1e-5f);                         \
      float gh = (V[r] - mean) * rstd * GC + BEC;                             \
      float fg = __shfl_down(gh, 4);                                          \
      float gg = __shfl_down(gh, 8);                                          \
      float og = __shfl_down(gh, 12);                                         \
      if (c16 < 4) {                                                          \
        float iv = sigm(gh), fv = sigm(fg), zv = tanh_fast(gg), ov = sigm(og); \
        float cc = fv * CS[r] + iv * zv;                                      \
        CS[r] = cc;                                                           \
        float hv = ov * tanh_fast(cc);                                        \
        int idx = row * 2048 + (HB) + colgrp * 4 + c16;                       \
        _Float16 h1v = (_Float16)hv;                                          \
        st_h_coh(&hch[idx], h1v);                                             \
        st_h_coh(&hcm[idx], (_Float16)((hv - (float)h1v) * 2048.0f));         \
      }                                                                       \
    } }

  f32x4_t ahe, aho, ame, amo;     // layer-0 accumulators
  f32x4_t dhe, dho, dme, dmo;     // layer-1 accumulators
  f32x4_t a0, d0;

#define A0_COMPUTE(TT) {                                                      \
    ahe = {0,0,0,0}; aho = {0,0,0,0}; ame = {0,0,0,0}; amo = {0,0,0,0};       \
    const float* xp = xbase + (size_t)(TT) * 512 + klo * 8;                   \
    _Pragma("unroll 2")                                                       \
    for (int kb = 0; kb < 16; kb += 2) {                                      \
      X_BODY(kb,     ahe, ame);                                               \
      X_BODY(kb + 1, aho, amo);                                               \
    }                                                                         \
    _Pragma("unroll 2")                                                       \
    for (int kb = 0; kb < 32; kb += 2) {                                      \
      H0_BODY(kb,     ahe, ame);                                              \
      H0_BODY(kb + 1, aho, amo);                                              \
    }                                                                         \
    a0 = (ahe + aho) * 0.03125f + (ame + amo) * (1.0f / 65536.0f);            \
    _Pragma("unroll")                                                         \
    for (int r_ = 0; r_ < 4; ++r_) a0[r_] += b0v; }

  // ---------------- prologue: A0[0] ----------------
  A0_COMPUTE(0);
  STAT_ADD(a0, 0);
  gridbar(bars, wgid, tid, ++ep);
  CELL(a0, 0, c0s, g0v, be0v, 0);
  gridbar(bars, wgid, tid, ++ep);

  // ---------------- main loop ----------------
  for (int t = 0; t < 512; ++t) {
    const int par = t & 1;
    const int npar = 1 - par;

    // ===== alpha[t]: A1[t] (+ A0[t+1]) =====
    dhe = {0,0,0,0}; dho = {0,0,0,0}; dme = {0,0,0,0}; dmo = {0,0,0,0};
    #pragma unroll 2
    for (int kb = 0; kb < 64; kb += 2) {
      H1_BODY(kb,     dhe, dme);
      H1_BODY(kb + 1, dho, dmo);
    }
    d0 = (dhe + dho) * 0.03125f + (dme + dmo) * (1.0f / 65536.0f);
    #pragma unroll
    for (int r = 0; r < 4; ++r) d0[r] += b1v;
    STAT_ADD(d0, 2 + par);

    if (t < 511) {
      A0_COMPUTE(t + 1);
      STAT_ADD(a0, npar);
    }

    // zero the buffers alpha[t+1] will accumulate: 16 replicas x 256 entries,
    // 8 WGs x 512 thr each cover {replica = wgid*2 + tid>>8, entry = tid&255}
    {
      int rep2 = ((wgid & 7) << 1) + (tid >> 8);
      int ent  = tid & 255;
      if (wgid < 8)       st_f_coh(&stats[((rep2 << 2) + 2 + npar) * 256 + ent], 0.0f);
      else if (wgid < 16) st_f_coh(&stats[((rep2 << 2) + par) * 256 + ent], 0.0f);
    }

    gridbar(bars, wgid, tid, ++ep);

    // ===== beta[t]: B1[t] (+ B0[t+1]) =====
    CELL(d0, 2 + par, c1s, g1v, be1v, 1024);
    if (t < 511) {
      CELL(a0, npar, c0s, g0v, be0v, 0);
    }
    gridbar(bars, wgid, tid, ++ep);
  }

  // ---------------- final fc: out = h1 @ fcW + fcb ----------------
  {
    int gid = wgid * 512 + tid;        // 131072 threads; 65536 outputs
    if (gid < 65536) {
      int b = gid >> 9, o = gid & 511;
      const _Float16* p1 = hch + (size_t)b * 2048 + 1024;
      const _Float16* p2 = hcm + (size_t)b * 2048 + 1024;
      float s = fcb[o];
      #pragma unroll 4
      for (int k = 0; k < 1024; k += 4) {
        union { u64 q; _Float16 h[4]; } ua, um;
        ua.q = __hip_atomic_load((u64*)(p1 + k), __ATOMIC_RELAXED, __HIP_MEMORY_SCOPE_SYSTEM);
        um.q = __hip_atomic_load((u64*)(p2 + k), __ATOMIC_RELAXED, __HIP_MEMORY_SCOPE_SYSTEM);
        #pragma unroll
        for (int i = 0; i < 4; ++i) {
          float h = (float)ua.h[i] + (float)um.h[i] * (1.0f / 2048.0f);
          s = fmaf(h, fcW[(k + i) * 512 + o], s);
        }
      }
      out[gid] = s;
    }
  }
}

extern "C" void kernel_launch(void* const* d_in, const int* in_sizes, int n_in,
                              void* d_out, int out_size, void* d_ws, size_t ws_size,
                              hipStream_t stream) {
  const float* x   = (const float*)d_in[0];
  const float* W0  = (const float*)d_in[1];
  const float* b0  = (const float*)d_in[2];
  const float* g0  = (const float*)d_in[3];
  const float* be0 = (const float*)d_in[4];
  const float* W1  = (const float*)d_in[5];
  const float* b1  = (const float*)d_in[6];
  const float* g1  = (const float*)d_in[7];
  const float* be1 = (const float*)d_in[8];
  const float* fcW = (const float*)d_in[9];
  const float* fcb = (const float*)d_in[10];
  float* out = (float*)d_out;

  char* ws = (char*)d_ws;
  _Float16* W0a  = (_Float16*)(ws);
  _Float16* W0b  = (_Float16*)(ws + 12582912);
  _Float16* W1a  = (_Float16*)(ws + 25165824);
  _Float16* W1b  = (_Float16*)(ws + 41943040);
  float* vecs    = (float*)(ws + 58720256);
  _Float16* hch  = (_Float16*)(ws + 58818560);
  _Float16* hcm  = (_Float16*)(ws + 59342848);
  float* stats   = (float*)(ws + 59867136);
  unsigned* bars = (unsigned*)(ws + 59932672);

  // re-zero h planes + stats + barrier state every call (graph replays reuse ws)
  hipMemsetAsync(hch, 0, 524288 + 524288 + 65536 + 8192, stream);
  lstm_prep<<<7264, 256, 0, stream>>>(W0, W1, b0, g0, be0, b1, g1, be1,
                                      W0a, W0b, W1a, W1b, vecs);

  hipFuncSetAttribute((const void*)lstm_seq,
                      hipFuncAttributeMaxDynamicSharedMemorySize, LDS_BYTES);
  void* args[] = { (void*)&x, (void*)&W0a, (void*)&W0b, (void*)&W1a, (void*)&W1b,
                   (void*)&vecs, (void*)&hch, (void*)&hcm,
                   (void*)&stats, (void*)&bars,
                   (void*)&fcW, (void*)&fcb, (void*)&out };
  hipLaunchCooperativeKernel((const void*)lstm_seq, dim3(256), dim3(512),
                             args, LDS_BYTES, stream);
}

// Round 10
// 40902.985 us; speedup vs baseline: 1.8914x; 1.8914x over previous
//
#include <hip/hip_runtime.h>
#include <hip/hip_bf16.h>

typedef __attribute__((ext_vector_type(8))) _Float16 half8_t;
typedef __attribute__((ext_vector_type(4))) float f32x4_t;
typedef unsigned long long u64;

#define SH 2056                       // LDS h row stride (elems): 2048 + 8 (16B-aligned, ~2-way banks)
#define HMOFF (16 * SH)               // plane-2 offset (elems)
#define LDS_BYTES (2 * 16 * SH * 2)   // 131,584 B -> 1 WG/CU, 8 waves = 2/SIMD

__device__ __forceinline__ float sigm(float z) { return 1.0f / (1.0f + __expf(-z)); }
__device__ __forceinline__ float tanh_fast(float z) {
  float e = __expf(2.0f * z);
  return 1.0f - 2.0f / (e + 1.0f);
}

// ---- coherent (cross-XCD) access helpers
__device__ __forceinline__ half8_t ld_h8_coh(const _Float16* p) {
  union { half8_t h; u64 q[2]; } r;
  u64* q = (u64*)p;
  r.q[0] = __hip_atomic_load(q,     __ATOMIC_RELAXED, __HIP_MEMORY_SCOPE_SYSTEM);
  r.q[1] = __hip_atomic_load(q + 1, __ATOMIC_RELAXED, __HIP_MEMORY_SCOPE_SYSTEM);
  return r.h;
}
__device__ __forceinline__ void st_h_coh(_Float16* p, _Float16 v) {
  unsigned short b = __builtin_bit_cast(unsigned short, v);
  __hip_atomic_store((unsigned short*)p, b, __ATOMIC_RELAXED, __HIP_MEMORY_SCOPE_SYSTEM);
}
__device__ __forceinline__ float ld_f_coh(const float* p) {
  return __hip_atomic_load((float*)p, __ATOMIC_RELAXED, __HIP_MEMORY_SCOPE_SYSTEM);
}
__device__ __forceinline__ void st_f_coh(float* p, float v) {
  __hip_atomic_store(p, v, __ATOMIC_RELAXED, __HIP_MEMORY_SCOPE_SYSTEM);
}

// ws layout (bytes) — total 59,940,864 (identical to r9, known-good):
//   W0a  @ 0         : 12582912   (fp16 plane1 = fp16(32*w), [gp][k])
//   W0b  @ 12582912  : 12582912
//   W1a  @ 25165824  : 16777216
//   W1b  @ 41943040  : 16777216
//   vecs @ 58720256  : 98304
//   hch  @ 58818560  : 524288     (h plane1 fp16, [row][h0|h1])
//   hcm  @ 59342848  : 524288     (h plane2 fp16, residual*2048)
//   stats@ 59867136  : 65536      (16 reps x 4 bufs x 256 f32)
//   bars @ 59932672  : 8192

// permutation (128-col WG groups): gp = colgrp*128 + w*16 + c,
//   gate = c>>2, uo = c&3 ; gcol = gate*1024 + colgrp*32 + w*4 + uo
__global__ void lstm_prep(const float* __restrict__ W0, const float* __restrict__ W1,
                          const float* __restrict__ b0, const float* __restrict__ g0,
                          const float* __restrict__ be0, const float* __restrict__ b1,
                          const float* __restrict__ g1, const float* __restrict__ be1,
                          _Float16* __restrict__ W0a, _Float16* __restrict__ W0b,
                          _Float16* __restrict__ W1a, _Float16* __restrict__ W1b,
                          float* __restrict__ vecs)
{
  int gid = blockIdx.x * 256 + threadIdx.x;
  const int W0N = 192 * 4096;
  const int W1N = 256 * 4096;
  if (gid < W0N) {
    int k8 = gid >> 12, gp = gid & 4095;
    int colgrp = gp >> 7, w = (gp >> 4) & 7, c = gp & 15;
    int gcol = ((c >> 2) << 10) + (colgrp << 5) + (w << 2) + (c & 3);
    half8_t va, vb;
    #pragma unroll
    for (int j = 0; j < 8; ++j) {
      float w32 = W0[(size_t)(k8 * 8 + j) * 4096 + gcol] * 32.0f;
      _Float16 p1 = (_Float16)w32;
      float r = w32 - (float)p1;
      va[j] = p1; vb[j] = (_Float16)(r * 2048.0f);
    }
    *(half8_t*)&W0a[(size_t)gp * 1536 + k8 * 8] = va;
    *(half8_t*)&W0b[(size_t)gp * 1536 + k8 * 8] = vb;
  } else if (gid < W0N + W1N) {
    int g2 = gid - W0N;
    int k8 = g2 >> 12, gp = g2 & 4095;
    int colgrp = gp >> 7, w = (gp >> 4) & 7, c = gp & 15;
    int gcol = ((c >> 2) << 10) + (colgrp << 5) + (w << 2) + (c & 3);
    half8_t va, vb;
    #pragma unroll
    for (int j = 0; j < 8; ++j) {
      float w32 = W1[(size_t)(k8 * 8 + j) * 4096 + gcol] * 32.0f;
      _Float16 p1 = (_Float16)w32;
      float r = w32 - (float)p1;
      va[j] = p1; vb[j] = (_Float16)(r * 2048.0f);
    }
    *(half8_t*)&W1a[(size_t)gp * 2048 + k8 * 8] = va;
    *(half8_t*)&W1b[(size_t)gp * 2048 + k8 * 8] = vb;
  } else if (gid < W0N + W1N + 6 * 4096) {
    int g2 = gid - W0N - W1N;
    int j = g2 >> 12, gp = g2 & 4095;
    int colgrp = gp >> 7, w = (gp >> 4) & 7, c = gp & 15;
    int gcol = ((c >> 2) << 10) + (colgrp << 5) + (w << 2) + (c & 3);
    const float* src = (j == 0) ? b0 : (j == 1) ? g0 : (j == 2) ? be0
                     : (j == 3) ? b1 : (j == 4) ? g1 : be1;
    vecs[j * 4096 + gp] = src[gcol];
  }
}

#define MFMA16(A, B, C) __builtin_amdgcn_mfma_f32_16x16x32_f16(A, B, C, 0, 0, 0)

// ---- fence-free grid barrier, 256 arrivals (r7-proven 8x32 structure)
__device__ __forceinline__ void gridbar(unsigned* bars, int wgid, int tid, unsigned ep) {
  __syncthreads();
  if (tid == 0) {
    const int q = ep & 1;
    unsigned old = __hip_atomic_fetch_add(&bars[(q * 8 + (wgid & 7)) * 32], 1u,
                                          __ATOMIC_RELAXED, __HIP_MEMORY_SCOPE_AGENT);
    if (old == 31u) {
      unsigned mo = __hip_atomic_fetch_add(&bars[512 + q * 32], 1u,
                                           __ATOMIC_RELAXED, __HIP_MEMORY_SCOPE_AGENT);
      if (mo == 7u) {
        #pragma unroll
        for (int g = 0; g < 8; ++g)
          __hip_atomic_store(&bars[(q * 8 + g) * 32], 0u, __ATOMIC_RELAXED, __HIP_MEMORY_SCOPE_SYSTEM);
        __hip_atomic_store(&bars[512 + q * 32], 0u, __ATOMIC_RELAXED, __HIP_MEMORY_SCOPE_SYSTEM);
        __hip_atomic_store(&bars[576], ep, __ATOMIC_RELEASE, __HIP_MEMORY_SCOPE_SYSTEM);
      }
    }
    while (__hip_atomic_load(&bars[576], __ATOMIC_RELAXED, __HIP_MEMORY_SCOPE_SYSTEM) < ep) {}
  }
  __syncthreads();
}

// 256 WGs x 512 thr. WG = (mtile = wgid>>5, colgrp = wgid&31); wave wid = 16-col
// tile within the WG's 128 columns. h staged in LDS once per step per WG.
__global__ void __launch_bounds__(512, 2) lstm_seq(
    const float* __restrict__ x,
    const _Float16* __restrict__ W0ap,
    const _Float16* __restrict__ W0bp,
    const _Float16* __restrict__ W1ap,
    const _Float16* __restrict__ W1bp,
    const float* __restrict__ vecs,
    _Float16* __restrict__ hch,
    _Float16* __restrict__ hcm,
    float* __restrict__ stats,
    unsigned* __restrict__ bars,
    const float* __restrict__ fcW,
    const float* __restrict__ fcb,
    float* __restrict__ out)
{
  extern __shared__ _Float16 hS[];    // [2 planes][16 rows][SH]
  const int tid = threadIdx.x;
  const int wgid = blockIdx.x;
  const int mtile = wgid >> 5;         // 0..7
  const int colgrp = wgid & 31;        // 0..31 (128-col group)
  const int wid = tid >> 6;            // 0..7 = 16-col tile
  const int lane = tid & 63;
  const int c16 = lane & 15;
  const int klo = lane >> 4;
  const int rowbase = mtile * 16;

  const int gp = colgrp * 128 + wid * 16 + c16;
  const float b0v  = vecs[gp];
  const float g0v  = vecs[4096 + gp];
  const float be0v = vecs[8192 + gp];
  const float b1v  = vecs[12288 + gp];
  const float g1v  = vecs[16384 + gp];
  const float be1v = vecs[20480 + gp];

  const int arow = rowbase + c16;
  const float* xbase = x + (size_t)arow * 512 * 512; // x[row][t][d]
  const _Float16* w0a = W0ap + (size_t)gp * 1536;
  const _Float16* w0b = W0bp + (size_t)gp * 1536;
  const _Float16* w1a = W1ap + (size_t)gp * 2048;
  const _Float16* w1b = W1bp + (size_t)gp * 2048;
  const int repbase = (wgid & 15) << 2;              // rep*4 for stats writes
  const int cbase = colgrp * 32 + wid * 4;           // h-unit base for this wave

  float c0s[4] = {0,0,0,0};
  float c1s[4] = {0,0,0,0};
  unsigned ep = 0;

// stage this WG's 16 h-rows (both planes, 2048 cols) -> LDS, coherently
#define STAGE_H() {                                                           \
    _Pragma("unroll")                                                         \
    for (int j = 0; j < 16; ++j) {                                            \
      int linear = tid + 512 * j;                                             \
      int plane = linear >> 12;                                               \
      int rem = linear & 4095;                                                \
      int row = rem >> 8;                                                     \
      int ck  = rem & 255;                                                    \
      const _Float16* srcp = (plane ? hcm : hch)                              \
                           + (size_t)(rowbase + row) * 2048 + ck * 8;         \
      *(half8_t*)&hS[plane * HMOFF + row * SH + ck * 8] = ld_h8_coh(srcp);    \
    }                                                                         \
    __syncthreads(); }

#define SPLIT2(E, J) { float e_ = (E); _Float16 h1_ = (_Float16)e_;           \
  float r_ = e_ - (float)h1_; ah[J] = h1_; am[J] = (_Float16)(r_ * 2048.0f); }

#define PROD3(HA, MA) \
  HA = MFMA16(ah, bh0, HA);                                                   \
  MA = MFMA16(ah, bm0, MA);                                                   \
  MA = MFMA16(am, bh0, MA);

#define X_BODY(KB, HA, MA) {                                                  \
      float4 xu = *(const float4*)(xp + (KB) * 32);                           \
      float4 xw = *(const float4*)(xp + (KB) * 32 + 4);                       \
      half8_t ah, am;                                                         \
      SPLIT2(xu.x, 0) SPLIT2(xu.y, 1) SPLIT2(xu.z, 2) SPLIT2(xu.w, 3)         \
      SPLIT2(xw.x, 4) SPLIT2(xw.y, 5) SPLIT2(xw.z, 6) SPLIT2(xw.w, 7)         \
      half8_t bh0 = *(const half8_t*)&w0a[(KB) * 32 + klo * 8];               \
      half8_t bm0 = *(const half8_t*)&w0b[(KB) * 32 + klo * 8];               \
      PROD3(HA, MA) }

#define H0_BODY(KB, HA, MA) {                                                 \
      half8_t ah = *(const half8_t*)&hS[c16 * SH + (KB) * 32 + klo * 8];      \
      half8_t am = *(const half8_t*)&hS[HMOFF + c16 * SH + (KB) * 32 + klo * 8]; \
      half8_t bh0 = *(const half8_t*)&w0a[512 + (KB) * 32 + klo * 8];         \
      half8_t bm0 = *(const half8_t*)&w0b[512 + (KB) * 32 + klo * 8];         \
      PROD3(HA, MA) }

#define H1_BODY(KB, HA, MA) {                                                 \
      half8_t ah = *(const half8_t*)&hS[c16 * SH + (KB) * 32 + klo * 8];      \
      half8_t am = *(const half8_t*)&hS[HMOFF + c16 * SH + (KB) * 32 + klo * 8]; \
      half8_t bh0 = *(const half8_t*)&w1a[(KB) * 32 + klo * 8];               \
      half8_t bm0 = *(const half8_t*)&w1b[(KB) * 32 + klo * 8];               \
      PROD3(HA, MA) }

#define STAT_ADD(V, BUF) {                                                    \
    _Pragma("unroll")                                                         \
    for (int r = 0; r < 4; ++r) {                                             \
      float s = V[r];                                                         \
      float q = V[r]*V[r];                                                    \
      _Pragma("unroll")                                                       \
      for (int m = 1; m <= 8; m <<= 1) { s += __shfl_xor(s, m); q += __shfl_xor(q, m); } \
      if (c16 == 0) {                                                         \
        int row = rowbase + klo * 4 + r;                                      \
        atomicAdd(&stats[(repbase + (BUF)) * 256 + row * 2 + 0], s);          \
        atomicAdd(&stats[(repbase + (BUF)) * 256 + row * 2 + 1], q);          \
      }                                                                       \
    } }

// LN + LSTM cell. Stats read: lane c16 loads replica c16, shuffle-sum (16 reps).
#define CELL(V, BUF, CS, GC, BEC, HB) {                                       \
    _Pragma("unroll")                                                         \
    for (int r = 0; r < 4; ++r) {                                             \
      int row = rowbase + klo * 4 + r;                                        \
      const float* sp = stats + ((c16 << 2) + (BUF)) * 256 + row * 2;         \
      float s_ = ld_f_coh(sp), q_ = ld_f_coh(sp + 1);                         \
      _Pragma("unroll")                                                       \
      for (int m = 1; m <= 8; m <<= 1) { s_ += __shfl_xor(s_, m); q_ += __shfl_xor(q_, m); } \
      float mean = s_ * (1.0f / 4096.0f);                                     \
      float msq  = q_ * (1.0f / 4096.0f);                                     \
      float rstd = rsqrtf(msq - mean * mean + 1e-5f);                         \
      float gh = (V[r] - mean) * rstd * GC + BEC;                             \
      float fg = __shfl_down(gh, 4);                                          \
      float gg = __shfl_down(gh, 8);                                          \
      float og = __shfl_down(gh, 12);                                         \
      if (c16 < 4) {                                                          \
        float iv = sigm(gh), fv = sigm(fg), zv = tanh_fast(gg), ov = sigm(og); \
        float cc = fv * CS[r] + iv * zv;                                      \
        CS[r] = cc;                                                           \
        float hv = ov * tanh_fast(cc);                                        \
        int idx = row * 2048 + (HB) + cbase + c16;                            \
        _Float16 h1v = (_Float16)hv;                                          \
        st_h_coh(&hch[idx], h1v);                                             \
        st_h_coh(&hcm[idx], (_Float16)((hv - (float)h1v) * 2048.0f));         \
      }                                                                       \
    } }

  f32x4_t ahe, aho, ame, amo;     // layer-0 accumulators
  f32x4_t dhe, dho, dme, dmo;     // layer-1 accumulators
  f32x4_t a0, d0;

#define A0_COMPUTE(TT) {                                                      \
    ahe = {0,0,0,0}; aho = {0,0,0,0}; ame = {0,0,0,0}; amo = {0,0,0,0};       \
    const float* xp = xbase + (size_t)(TT) * 512 + klo * 8;                   \
    _Pragma("unroll 2")                                                       \
    for (int kb = 0; kb < 16; kb += 2) {                                      \
      X_BODY(kb,     ahe, ame);                                               \
      X_BODY(kb + 1, aho, amo);                                               \
    }                                                                         \
    _Pragma("unroll 2")                                                       \
    for (int kb = 0; kb < 32; kb += 2) {                                      \
      H0_BODY(kb,     ahe, ame);                                              \
      H0_BODY(kb + 1, aho, amo);                                              \
    }                                                                         \
    a0 = (ahe + aho) * 0.03125f + (ame + amo) * (1.0f / 65536.0f);            \
    _Pragma("unroll")                                                         \
    for (int r_ = 0; r_ < 4; ++r_) a0[r_] += b0v; }

  // ---------------- prologue: A0[0] (h planes are zeroed) ----------------
  STAGE_H();
  A0_COMPUTE(0);
  STAT_ADD(a0, 0);
  gridbar(bars, wgid, tid, ++ep);
  CELL(a0, 0, c0s, g0v, be0v, 0);
  gridbar(bars, wgid, tid, ++ep);

  // ---------------- main loop ----------------
  for (int t = 0; t < 512; ++t) {
    const int par = t & 1;
    const int npar = 1 - par;

    // ===== alpha[t]: stage {h0[t], h1[t-1]}; A1[t] (+ A0[t+1]) =====
    STAGE_H();

    dhe = {0,0,0,0}; dho = {0,0,0,0}; dme = {0,0,0,0}; dmo = {0,0,0,0};
    #pragma unroll 2
    for (int kb = 0; kb < 64; kb += 2) {
      H1_BODY(kb,     dhe, dme);
      H1_BODY(kb + 1, dho, dmo);
    }
    d0 = (dhe + dho) * 0.03125f + (dme + dmo) * (1.0f / 65536.0f);
    #pragma unroll
    for (int r = 0; r < 4; ++r) d0[r] += b1v;
    STAT_ADD(d0, 2 + par);

    if (t < 511) {
      A0_COMPUTE(t + 1);
      STAT_ADD(a0, npar);
    }

    // zero the buffers alpha[t+1] will accumulate: 16 reps x 256 entries,
    // 8 WGs x 512 thr each: {replica = (wgid&7)*2 + tid>>8, entry = tid&255}
    {
      int rep2 = ((wgid & 7) << 1) + (tid >> 8);
      int ent  = tid & 255;
      if (wgid < 8)       st_f_coh(&stats[((rep2 << 2) + 2 + npar) * 256 + ent], 0.0f);
      else if (wgid < 16) st_f_coh(&stats[((rep2 << 2) + par) * 256 + ent], 0.0f);
    }

    gridbar(bars, wgid, tid, ++ep);

    // ===== beta[t]: B1[t] (+ B0[t+1]) =====
    CELL(d0, 2 + par, c1s, g1v, be1v, 1024);
    if (t < 511) {
      CELL(a0, npar, c0s, g0v, be0v, 0);
    }
    gridbar(bars, wgid, tid, ++ep);
  }

  // ---------------- final fc: out = h1 @ fcW + fcb ----------------
  {
    int gid = wgid * 512 + tid;        // 131072 threads; 65536 outputs
    if (gid < 65536) {
      int b = gid >> 9, o = gid & 511;
      const _Float16* p1 = hch + (size_t)b * 2048 + 1024;
      const _Float16* p2 = hcm + (size_t)b * 2048 + 1024;
      float s = fcb[o];
      #pragma unroll 4
      for (int k = 0; k < 1024; k += 4) {
        union { u64 q; _Float16 h[4]; } ua, um;
        ua.q = __hip_atomic_load((u64*)(p1 + k), __ATOMIC_RELAXED, __HIP_MEMORY_SCOPE_SYSTEM);
        um.q = __hip_atomic_load((u64*)(p2 + k), __ATOMIC_RELAXED, __HIP_MEMORY_SCOPE_SYSTEM);
        #pragma unroll
        for (int i = 0; i < 4; ++i) {
          float h = (float)ua.h[i] + (float)um.h[i] * (1.0f / 2048.0f);
          s = fmaf(h, fcW[(k + i) * 512 + o], s);
        }
      }
      out[gid] = s;
    }
  }
}

extern "C" void kernel_launch(void* const* d_in, const int* in_sizes, int n_in,
                              void* d_out, int out_size, void* d_ws, size_t ws_size,
                              hipStream_t stream) {
  const float* x   = (const float*)d_in[0];
  const float* W0  = (const float*)d_in[1];
  const float* b0  = (const float*)d_in[2];
  const float* g0  = (const float*)d_in[3];
  const float* be0 = (const float*)d_in[4];
  const float* W1  = (const float*)d_in[5];
  const float* b1  = (const float*)d_in[6];
  const float* g1  = (const float*)d_in[7];
  const float* be1 = (const float*)d_in[8];
  const float* fcW = (const float*)d_in[9];
  const float* fcb = (const float*)d_in[10];
  float* out = (float*)d_out;

  char* ws = (char*)d_ws;
  _Float16* W0a  = (_Float16*)(ws);
  _Float16* W0b  = (_Float16*)(ws + 12582912);
  _Float16* W1a  = (_Float16*)(ws + 25165824);
  _Float16* W1b  = (_Float16*)(ws + 41943040);
  float* vecs    = (float*)(ws + 58720256);
  _Float16* hch  = (_Float16*)(ws + 58818560);
  _Float16* hcm  = (_Float16*)(ws + 59342848);
  float* stats   = (float*)(ws + 59867136);
  unsigned* bars = (unsigned*)(ws + 59932672);

  // re-zero h planes + stats + barrier state every call (graph replays reuse ws)
  hipMemsetAsync(hch, 0, 524288 + 524288 + 65536 + 8192, stream);
  lstm_prep<<<7264, 256, 0, stream>>>(W0, W1, b0, g0, be0, b1, g1, be1,
                                      W0a, W0b, W1a, W1b, vecs);

  hipFuncSetAttribute((const void*)lstm_seq,
                      hipFuncAttributeMaxDynamicSharedMemorySize, LDS_BYTES);
  void* args[] = { (void*)&x, (void*)&W0a, (void*)&W0b, (void*)&W1a, (void*)&W1b,
                   (void*)&vecs, (void*)&hch, (void*)&hcm,
                   (void*)&stats, (void*)&bars,
                   (void*)&fcW, (void*)&fcb, (void*)&out };
  hipError_t lerr = hipLaunchCooperativeKernel((const void*)lstm_seq,
                                               dim3(256), dim3(512),
                                               args, LDS_BYTES, stream);
  if (lerr != hipSuccess) {
    // coop validator rejected (likely the >64KB-LDS occupancy calc). Grid=256
    // = #CUs at 1 WG/CU -> co-residency is capacity-guaranteed; plain launch.
    (void)hipGetLastError();
    lstm_seq<<<dim3(256), dim3(512), LDS_BYTES, stream>>>(
        x, W0a, W0b, W1a, W1b, vecs, hch, hcm, stats, bars, fcW, fcb, out);
  }
}